// Round 1
// baseline (491.532 us; speedup 1.0000x reference)
//
#include <hip/hip_runtime.h>

// BatchRenorm2d fwd (training, is_unlock=False): out = (x - mu_c) / sqrt(var_c + eps)
// x: [16, 64, 256, 256] fp32. Stats per channel over (B,H,W) = 1,048,576 elems.

#define EPS 1e-5f
#define NB 16
#define NC 64
#define HW 65536                 // 256*256, one (b,c) slab, contiguous
#define NSLAB (NB * NC)          // 1024
#define NPC ((float)(NB * HW))   // elems per channel = 1048576

// ---------------- Kernel 1: per-channel sum & sumsq ----------------
// One block per (b,c) slab. 256 threads, each loads 64 float4 (coalesced).
__global__ __launch_bounds__(256) void brn_reduce(const float* __restrict__ in,
                                                  float* __restrict__ stats) {
    const int slab = blockIdx.x;          // slab = b*64 + c
    const int c = slab & (NC - 1);
    const float4* __restrict__ p =
        reinterpret_cast<const float4*>(in + (size_t)slab * HW);
    const int t = threadIdx.x;

    float s = 0.f, ss = 0.f;
    #pragma unroll 8
    for (int k = 0; k < 64; ++k) {
        float4 v = p[t + (k << 8)];
        s  += (v.x + v.y) + (v.z + v.w);
        ss += (v.x * v.x + v.y * v.y) + (v.z * v.z + v.w * v.w);
    }

    // wave (64-lane) shuffle reduction
    #pragma unroll
    for (int off = 32; off > 0; off >>= 1) {
        s  += __shfl_down(s, off);
        ss += __shfl_down(ss, off);
    }

    __shared__ float ls[4], lss[4];
    const int wid = t >> 6;
    if ((t & 63) == 0) { ls[wid] = s; lss[wid] = ss; }
    __syncthreads();
    if (t == 0) {
        s  = (ls[0] + ls[1]) + (ls[2] + ls[3]);
        ss = (lss[0] + lss[1]) + (lss[2] + lss[3]);
        atomicAdd(&stats[c * 2 + 0], s);   // 16 blocks/channel contend — cheap
        atomicAdd(&stats[c * 2 + 1], ss);
    }
}

// ---------------- Kernel 2: normalize ----------------
__global__ __launch_bounds__(256) void brn_norm(const float* __restrict__ in,
                                                const float* __restrict__ stats,
                                                float* __restrict__ out) {
    const int slab = blockIdx.x;
    const int c = slab & (NC - 1);
    const float sum   = stats[c * 2 + 0];
    const float sumsq = stats[c * 2 + 1];
    const float invN = 1.0f / NPC;
    const float mu = sum * invN;
    const float var = sumsq * invN - mu * mu;       // E[x^2] - mu^2
    const float inv_sigma = 1.0f / sqrtf(var + EPS);

    const float4* __restrict__ p =
        reinterpret_cast<const float4*>(in + (size_t)slab * HW);
    float4* __restrict__ q = reinterpret_cast<float4*>(out + (size_t)slab * HW);
    const int t = threadIdx.x;

    #pragma unroll 8
    for (int k = 0; k < 64; ++k) {
        float4 v = p[t + (k << 8)];
        float4 r;
        r.x = (v.x - mu) * inv_sigma;
        r.y = (v.y - mu) * inv_sigma;
        r.z = (v.z - mu) * inv_sigma;
        r.w = (v.w - mu) * inv_sigma;
        q[t + (k << 8)] = r;
    }
}

extern "C" void kernel_launch(void* const* d_in, const int* in_sizes, int n_in,
                              void* d_out, int out_size, void* d_ws, size_t ws_size,
                              hipStream_t stream) {
    const float* in = (const float*)d_in[0];
    float* out = (float*)d_out;
    float* stats = (float*)d_ws;   // 64 channels x {sum, sumsq} = 512 B

    hipMemsetAsync(stats, 0, NC * 2 * sizeof(float), stream);
    brn_reduce<<<NSLAB, 256, 0, stream>>>(in, stats);
    brn_norm<<<NSLAB, 256, 0, stream>>>(in, stats, out);
}

// Round 2
// 469.020 us; speedup vs baseline: 1.0480x; 1.0480x over previous
//
#include <hip/hip_runtime.h>

// BatchRenorm2d fwd (training, is_unlock=False): out = (x - mu_c) / sqrt(var_c + eps)
// x: [16, 64, 256, 256] fp32, contiguous. Stats per channel over (B,H,W).
// Two-pass, no atomics, no memset:
//   K1: per-(b,c)-slab partial {sum, sumsq} -> d_ws slot (distinct per block)
//   K2: sum 16 partials per channel, normalize, nontemporal stores.

#define EPS 1e-5f
#define NB 16
#define NC 64
#define HW 65536                 // 256*256, one (b,c) slab, contiguous
#define NSLAB (NB * NC)          // 1024
#define NPC ((float)(NB * HW))   // elems per channel = 1048576

typedef float f32x4 __attribute__((ext_vector_type(4)));

// ---------------- Kernel 1: per-slab partial sums ----------------
// One block per (b,c) slab. 256 threads, each loads 64 float4 (coalesced).
__global__ __launch_bounds__(256) void brn_reduce(const float* __restrict__ in,
                                                  float* __restrict__ part) {
    const int slab = blockIdx.x;          // slab = b*64 + c
    const f32x4* __restrict__ p =
        reinterpret_cast<const f32x4*>(in + (size_t)slab * HW);
    const int t = threadIdx.x;

    // two independent accumulator chains (shorter dep chains, more ILP)
    float s0 = 0.f, s1 = 0.f, ss0 = 0.f, ss1 = 0.f;
    #pragma unroll 8
    for (int k = 0; k < 64; k += 2) {
        f32x4 a = p[t + (k << 8)];
        f32x4 b = p[t + ((k + 1) << 8)];
        s0  += (a.x + a.y) + (a.z + a.w);
        ss0 += (a.x * a.x + a.y * a.y) + (a.z * a.z + a.w * a.w);
        s1  += (b.x + b.y) + (b.z + b.w);
        ss1 += (b.x * b.x + b.y * b.y) + (b.z * b.z + b.w * b.w);
    }
    float s = s0 + s1, ss = ss0 + ss1;

    // wave (64-lane) shuffle reduction
    #pragma unroll
    for (int off = 32; off > 0; off >>= 1) {
        s  += __shfl_down(s, off);
        ss += __shfl_down(ss, off);
    }

    __shared__ float ls[4], lss[4];
    const int wid = t >> 6;
    if ((t & 63) == 0) { ls[wid] = s; lss[wid] = ss; }
    __syncthreads();
    if (t == 0) {
        part[slab * 2 + 0] = (ls[0] + ls[1]) + (ls[2] + ls[3]);
        part[slab * 2 + 1] = (lss[0] + lss[1]) + (lss[2] + lss[3]);
    }
}

// ---------------- Kernel 2: normalize ----------------
__global__ __launch_bounds__(256) void brn_norm(const float* __restrict__ in,
                                                const float* __restrict__ part,
                                                float* __restrict__ out) {
    // Reverse slab order: read most-recently-touched slabs first (L3 LRU friendly).
    const int slab = (NSLAB - 1) - blockIdx.x;
    const int c = slab & (NC - 1);

    __shared__ float smu, sis;
    if (threadIdx.x == 0) {
        float s = 0.f, ss = 0.f;
        #pragma unroll
        for (int b = 0; b < NB; ++b) {
            const int sl = (b << 6) | c;
            s  += part[sl * 2 + 0];
            ss += part[sl * 2 + 1];
        }
        const float mu  = s / NPC;
        const float var = ss / NPC - mu * mu;     // E[x^2] - mu^2
        smu = mu;
        sis = 1.0f / sqrtf(var + EPS);
    }
    __syncthreads();
    const float mu = smu, is = sis;

    const f32x4* __restrict__ p =
        reinterpret_cast<const f32x4*>(in + (size_t)slab * HW);
    f32x4* __restrict__ q = reinterpret_cast<f32x4*>(out + (size_t)slab * HW);
    const int t = threadIdx.x;

    #pragma unroll 8
    for (int k = 0; k < 64; ++k) {
        f32x4 v = p[t + (k << 8)];
        f32x4 r;
        r.x = (v.x - mu) * is;
        r.y = (v.y - mu) * is;
        r.z = (v.z - mu) * is;
        r.w = (v.w - mu) * is;
        // nt store: don't pollute L3 -> input stays resident for this pass's reads
        __builtin_nontemporal_store(r, &q[t + (k << 8)]);
    }
}

extern "C" void kernel_launch(void* const* d_in, const int* in_sizes, int n_in,
                              void* d_out, int out_size, void* d_ws, size_t ws_size,
                              hipStream_t stream) {
    const float* in = (const float*)d_in[0];
    float* out = (float*)d_out;
    float* part = (float*)d_ws;   // 1024 slabs x {sum, sumsq} = 8 KB, fully overwritten

    brn_reduce<<<NSLAB, 256, 0, stream>>>(in, part);
    brn_norm<<<NSLAB, 256, 0, stream>>>(in, part, out);
}